// Round 2
// baseline (2308.231 us; speedup 1.0000x reference)
//
#include <hip/hip_runtime.h>
#include <hip/hip_fp16.h>

typedef _Float16 f16;
typedef _Float16 f16x8 __attribute__((ext_vector_type(8)));
typedef float f32x4 __attribute__((ext_vector_type(4)));
typedef unsigned char u8;

#define HDIM 256
#define TST 128
#define OUTD 10
#define S2LE 2.8853900817779268f   // 2*log2(e): folded into W/ub so tanh needs no arg-scale

// One block = 4 waves; each wave owns 16 batch cols and the FULL 256 hidden.
// Zero barriers in the 128-step loop: LN reduce = 2 shfl_xor, B-frag pack is
// lane-local (k = c*32 + q*4 + (j&3) + 16*(j>>2) == n = nt*16+q*4+r with
// nt=2c+(j>>2), r=j&3). W split: n-tiles 0..7 in 256 VGPRs, 8..15 streamed
// from LDS (dbuf). gamma folded into W cols / tables; 2log2e into W/biases.
__global__ __launch_bounds__(256, 1) void rnn_kernel(
    const float* __restrict__ x,
    const float* __restrict__ embed_w,
    const float* __restrict__ embed_b,
    const float* __restrict__ update_w,
    const float* __restrict__ update_b,
    const float* __restrict__ gamma,
    const float* __restrict__ beta,
    const float* __restrict__ out_w,
    const float* __restrict__ out_b,
    float* __restrict__ out)
{
  __shared__ __align__(16) f16   sWs[8][8][64][8];   // [c][nt-8][lane][j] 64 KB streamed half
  __shared__ __align__(16) f16   sTB[8][4][10][8];   // T[xv][k]/g[k] in frag order, 5 KB
  __shared__ __align__(16) float sUB[2][16][4][4];   // S2LE*(ub [+ beta@W^T]), 2 KB
  __shared__ __align__(16) f16   sOW[8][64][8];      // g[k]*out_w frags, 8 KB
  __shared__ float sOB[16];
  __shared__ u8    sXb[TST][64];                     // x as u8, 8 KB

  const int tid = threadIdx.x;
  const int w  = tid >> 6;
  const int l  = tid & 63;
  const int q  = l >> 4;
  const int ml = l & 15;
  const int base = blockIdx.x * 64;

  // ---------------- init ----------------
  // x -> u8 table
  for (int idx = tid; idx < 64 * TST; idx += 256) {
    int m = idx >> 7, tt = idx & 127;
    sXb[tt][m] = (u8)(int)x[(size_t)(base + m) * TST + tt];
  }
  // input table, /gamma
  for (int e = tid; e < 2560; e += 256) {
    int j = e & 7, r1 = e >> 3, xv = r1 % 10, r2 = r1 / 10, q2 = r2 & 3, c = r2 >> 2;
    int k = c * 32 + q2 * 4 + (j & 3) + 16 * (j >> 2);
    float v = tanhf((float)xv * embed_w[k] + embed_b[k]) * __builtin_amdgcn_rcpf(gamma[k]);
    sTB[c][q2][xv][j] = (f16)v;
  }
  // biases (scaled by S2LE)
  {
    int n = tid;
    float u = update_b[n];
    float a = 0.f;
    const float* wrow = update_w + n * HDIM;
    for (int k2 = 0; k2 < HDIM; k2 += 4) {
      float4 wb = *(const float4*)(wrow + k2);
      float4 bb = *(const float4*)(beta + k2);
      a = fmaf(wb.x, bb.x, fmaf(wb.y, bb.y, fmaf(wb.z, bb.z, fmaf(wb.w, bb.w, a))));
    }
    int nt = n >> 4, qq = (n >> 2) & 3, rr = n & 3;
    sUB[0][nt][qq][rr] = S2LE * u;
    sUB[1][nt][qq][rr] = S2LE * (u + a);
  }
  // streamed W half (n-tiles 8..15), scaled S2LE*gamma
  for (int idx = tid; idx < 4096; idx += 256) {
    int c = idx >> 9, nt8 = (idx >> 6) & 7, l2 = idx & 63;
    int q2 = l2 >> 4, ml2 = l2 & 15;
    int n = (8 + nt8) * 16 + ml2, k0 = c * 32 + q2 * 4;
    const float* wrow = update_w + n * HDIM;
    float4 a0 = *(const float4*)(wrow + k0);
    float4 a1 = *(const float4*)(wrow + k0 + 16);
    float4 g0 = *(const float4*)(gamma + k0);
    float4 g1 = *(const float4*)(gamma + k0 + 16);
    f16x8 f;
    f[0] = (f16)(S2LE * g0.x * a0.x); f[1] = (f16)(S2LE * g0.y * a0.y);
    f[2] = (f16)(S2LE * g0.z * a0.z); f[3] = (f16)(S2LE * g0.w * a0.w);
    f[4] = (f16)(S2LE * g1.x * a1.x); f[5] = (f16)(S2LE * g1.y * a1.y);
    f[6] = (f16)(S2LE * g1.z * a1.z); f[7] = (f16)(S2LE * g1.w * a1.w);
    *(f16x8*)&sWs[c][nt8][l2][0] = f;
  }
  // out_w frags (gamma folded, NO S2LE), rows >= OUTD zero-padded
  for (int idx = tid; idx < 512; idx += 256) {
    int c = idx >> 6, l2 = idx & 63, q2 = l2 >> 4, o = l2 & 15;
    int k0 = c * 32 + q2 * 4;
    f16x8 f;
    #pragma unroll
    for (int j = 0; j < 8; j++) f[j] = (f16)0.f;
    if (o < OUTD) {
      const float* orow = out_w + o * HDIM;
      float4 a0 = *(const float4*)(orow + k0);
      float4 a1 = *(const float4*)(orow + k0 + 16);
      float4 g0 = *(const float4*)(gamma + k0);
      float4 g1 = *(const float4*)(gamma + k0 + 16);
      f[0] = (f16)(g0.x * a0.x); f[1] = (f16)(g0.y * a0.y);
      f[2] = (f16)(g0.z * a0.z); f[3] = (f16)(g0.w * a0.w);
      f[4] = (f16)(g1.x * a1.x); f[5] = (f16)(g1.y * a1.y);
      f[6] = (f16)(g1.z * a1.z); f[7] = (f16)(g1.w * a1.w);
    }
    *(f16x8*)&sOW[c][l2][0] = f;
  }
  // output bias (+ beta @ out_w^T)
  if (tid < 16) {
    float v = 0.f;
    if (tid < OUTD) {
      v = out_b[tid];
      const float* orow = out_w + tid * HDIM;
      for (int k2 = 0; k2 < HDIM; k2 += 4) {
        float4 wv = *(const float4*)(orow + k2);
        float4 bv = *(const float4*)(beta + k2);
        v = fmaf(wv.x, bv.x, fmaf(wv.y, bv.y, fmaf(wv.z, bv.z, fmaf(wv.w, bv.w, v))));
      }
    }
    sOB[tid] = v;
  }
  // register-resident W half (n-tiles 0..7), scaled S2LE*gamma
  f16x8 wr[8][8];  // [nt][c]
  #pragma unroll
  for (int c = 0; c < 8; c++) {
    const int k0 = c * 32 + q * 4;
    float4 g0 = *(const float4*)(gamma + k0);
    float4 g1 = *(const float4*)(gamma + k0 + 16);
    #pragma unroll
    for (int nt = 0; nt < 8; nt++) {
      const float* wrow = update_w + (nt * 16 + ml) * HDIM;
      float4 a0 = *(const float4*)(wrow + k0);
      float4 a1 = *(const float4*)(wrow + k0 + 16);
      f16x8 f;
      f[0] = (f16)(S2LE * g0.x * a0.x); f[1] = (f16)(S2LE * g0.y * a0.y);
      f[2] = (f16)(S2LE * g0.z * a0.z); f[3] = (f16)(S2LE * g0.w * a0.w);
      f[4] = (f16)(S2LE * g1.x * a1.x); f[5] = (f16)(S2LE * g1.y * a1.y);
      f[6] = (f16)(S2LE * g1.z * a1.z); f[7] = (f16)(S2LE * g1.w * a1.w);
      wr[nt][c] = f;
    }
  }
  __syncthreads();   // the ONLY barrier before the recurrence

  // ---------------- recurrence ----------------
  const int mcol = w * 16 + ml;
  f16x8 bf[8];
  {
    const int xv0 = (int)sXb[0][mcol];
    #pragma unroll
    for (int c = 0; c < 8; c++) bf[c] = *(const f16x8*)&sTB[c][q][xv0][0];
  }

  f32x4 acc[16];
  float mu = 0.f, rs = 1.f;

  #pragma unroll 1
  for (int t = 0; t < TST; t++) {
    const int xn = (t < TST - 1) ? (int)sXb[t + 1][mcol] : 0;
    const int sel = (t > 0) ? 1 : 0;
    #pragma unroll
    for (int nt = 0; nt < 16; nt++)
      acc[nt] = *(const f32x4*)&sUB[sel][nt][q][0];

    f16x8 wsA[8], wsB[8];
    #pragma unroll
    for (int n8 = 0; n8 < 8; n8++) wsA[n8] = *(const f16x8*)&sWs[0][n8][l][0];

#define STEP_C(c, CUR, NXT)                                                      \
    {                                                                            \
      if ((c) < 7) {                                                             \
        _Pragma("unroll")                                                        \
        for (int n8 = 0; n8 < 8; n8++)                                           \
          NXT[n8] = *(const f16x8*)&sWs[(c) + 1][n8][l][0];                      \
      }                                                                          \
      _Pragma("unroll")                                                          \
      for (int nt = 0; nt < 8; nt++)                                             \
        acc[nt] = __builtin_amdgcn_mfma_f32_16x16x32_f16(wr[nt][(c)], bf[(c)],   \
                                                         acc[nt], 0, 0, 0);      \
      _Pragma("unroll")                                                          \
      for (int n8 = 0; n8 < 8; n8++)                                             \
        acc[8 + n8] = __builtin_amdgcn_mfma_f32_16x16x32_f16(CUR[n8], bf[(c)],   \
                                                             acc[8 + n8], 0, 0, 0); \
    }
    STEP_C(0, wsA, wsB)
    STEP_C(1, wsB, wsA)
    STEP_C(2, wsA, wsB)
    STEP_C(3, wsB, wsA)
    STEP_C(4, wsA, wsB)
    STEP_C(5, wsB, wsA)
    STEP_C(6, wsA, wsB)
    STEP_C(7, wsB, wsA)
#undef STEP_C

    // tanh (arg pre-scaled by 2log2e) + LN stats, 4-way partial chains
    float p1[4] = {0.f, 0.f, 0.f, 0.f};
    float p2[4] = {0.f, 0.f, 0.f, 0.f};
    #pragma unroll
    for (int nt = 0; nt < 16; nt++) {
      #pragma unroll
      for (int r = 0; r < 4; r++) {
        float e  = __builtin_amdgcn_exp2f(acc[nt][r]);
        float tv = 1.f - 2.f * __builtin_amdgcn_rcpf(e + 1.f);
        acc[nt][r] = tv;
        p1[nt & 3] += tv;
        p2[nt & 3] = fmaf(tv, tv, p2[nt & 3]);
      }
    }
    float s1 = (p1[0] + p1[1]) + (p1[2] + p1[3]);
    float s2 = (p2[0] + p2[1]) + (p2[2] + p2[3]);
    s1 += __shfl_xor(s1, 16, 64);  s2 += __shfl_xor(s2, 16, 64);
    s1 += __shfl_xor(s1, 32, 64);  s2 += __shfl_xor(s2, 32, 64);
    mu = s1 * (1.f / 256.f);
    float var = fmaf(s2, 1.f / 256.f, -mu * mu);
    rs = __frsqrt_rn(var + 1e-5f);

    if (t < TST - 1) {
      #pragma unroll
      for (int c = 0; c < 8; c++) {
        f16x8 tb = *(const f16x8*)&sTB[c][q][xn][0];
        f16x8 af;
        #pragma unroll
        for (int j = 0; j < 8; j++) {
          float z = (acc[2 * c + (j >> 2)][j & 3] - mu) * rs;
          af[j] = (f16)((float)tb[j] + z);
        }
        bf[c] = af;
      }
    }
  }

  // ---------------- output projection via MFMA ----------------
  f32x4 aO = {0.f, 0.f, 0.f, 0.f};
  #pragma unroll
  for (int c = 0; c < 8; c++) {
    f16x8 af;
    #pragma unroll
    for (int j = 0; j < 8; j++) {
      float z = (acc[2 * c + (j >> 2)][j & 3] - mu) * rs;
      af[j] = (f16)z;
    }
    f16x8 of = *(const f16x8*)&sOW[c][l][0];
    aO = __builtin_amdgcn_mfma_f32_16x16x32_f16(of, af, aO, 0, 0, 0);
  }
  const int row = base + mcol;
  #pragma unroll
  for (int r = 0; r < 4; r++) {
    const int o = q * 4 + r;
    if (o < OUTD) out[(size_t)row * OUTD + o] = aO[r] + sOB[o];
  }
}

extern "C" void kernel_launch(void* const* d_in, const int* in_sizes, int n_in,
                              void* d_out, int out_size, void* d_ws, size_t ws_size,
                              hipStream_t stream) {
  const float* x   = (const float*)d_in[0];
  const float* ew  = (const float*)d_in[1];
  const float* eb  = (const float*)d_in[2];
  const float* uw  = (const float*)d_in[3];
  const float* ub  = (const float*)d_in[4];
  const float* g   = (const float*)d_in[5];
  const float* be  = (const float*)d_in[6];
  const float* ow  = (const float*)d_in[7];
  const float* ob  = (const float*)d_in[8];
  float* out = (float*)d_out;

  const int B = in_sizes[0] / TST;      // 16384
  const int grid = B / 64;              // 256 blocks, 1 per CU
  hipLaunchKernelGGL(rnn_kernel, dim3(grid), dim3(256), 0, stream,
                     x, ew, eb, uw, ub, g, be, ow, ob, out);
}

// Round 3
// 426.096 us; speedup vs baseline: 5.4172x; 5.4172x over previous
//
#include <hip/hip_runtime.h>
#include <hip/hip_fp16.h>
#include <math.h>

typedef _Float16 f16;
typedef _Float16 f16x8 __attribute__((ext_vector_type(8)));
typedef float f32x4 __attribute__((ext_vector_type(4)));
typedef unsigned char u8;

#define HDIM 256
#define TST 128
#define OUTD 10
#define S2LE 2.8853900817779268f   // 2*log2(e)

// R1 structure (4 waves split hidden, 16 batch cols/block) + LN-through-matmul:
//   y_scaled = rs*(W_g @ tv) - rs*mu*RSg[n] + D[xv][n],  W_g = S2LE*gamma_k*W[n][k]
// B-frag for next step = f16(tv) only -> stats off the critical path,
// ONE barrier per step (double-buffered sFrag/sStats to avoid WAR race).
__global__ __launch_bounds__(256, 2) void rnn_kernel(
    const float* __restrict__ x,
    const float* __restrict__ embed_w,
    const float* __restrict__ embed_b,
    const float* __restrict__ update_w,
    const float* __restrict__ update_b,
    const float* __restrict__ gamma,
    const float* __restrict__ beta,
    const float* __restrict__ out_w,
    const float* __restrict__ out_b,
    float* __restrict__ out)
{
  __shared__ __align__(16) f16   sFrag[2][8][64][8];   // 16 KB, double-buffered
  __shared__ __align__(16) float sD1[10 * 260];        // 10.4 KB, pad 260 -> <=2-way conflicts
  __shared__ __align__(16) float sBW[HDIM];            // S2LE * (beta @ W^T)
  __shared__ __align__(16) float sRSg[HDIM];           // rowsum of W_g
  __shared__ __align__(16) float sOvl[3072];           // overlay: T0[256][10] -> sOW(2048 f) + sOut(1024 f)
  __shared__ float sStats[2][4][16][2];
  __shared__ float sOB[16];
  __shared__ u8    sXb[TST][16];

  const int tid = threadIdx.x;
  const int w  = tid >> 6;
  const int l  = tid & 63;
  const int q  = l >> 4;
  const int ml = l & 15;
  const int base = blockIdx.x * 16;
  const int nb = w * 64 + q * 4;     // n = nb + nt*16 + r

  // ---------- P1: T0 table (tanh(xv*ew+eb)), x->u8, out bias ----------
  {
    float ew = embed_w[tid], eb = embed_b[tid];
    #pragma unroll
    for (int xv = 0; xv < 10; xv++)
      sOvl[tid * 10 + xv] = tanhf((float)xv * ew + eb);
  }
  for (int idx = tid; idx < 16 * TST; idx += 256) {
    int m = idx >> 7, tt = idx & 127;
    sXb[tt][m] = (u8)(int)x[(size_t)(base + m) * TST + tt];
  }
  if (tid < 16) {
    float v = 0.f;
    if (tid < OUTD) {
      v = out_b[tid];
      const float* orow = out_w + tid * HDIM;
      for (int k = 0; k < HDIM; k += 4) {
        float4 wv = *(const float4*)(orow + k);
        float4 bv = *(const float4*)(beta + k);
        v = fmaf(wv.x, bv.x, fmaf(wv.y, bv.y, fmaf(wv.z, bv.z, fmaf(wv.w, bv.w, v))));
      }
    }
    sOB[tid] = v;
  }
  __syncthreads();

  // ---------- P2: per-n tables TY/betaW/RSg -> sD1, sBW, sRSg ----------
  {
    const int n = tid;
    const float* wrow = update_w + n * HDIM;
    float ty[10];
    #pragma unroll
    for (int xv = 0; xv < 10; xv++) ty[xv] = 0.f;
    float bw = 0.f, rsg = 0.f;
    for (int k = 0; k < HDIM; k += 4) {
      float4 wv4 = *(const float4*)(wrow + k);
      float4 b4  = *(const float4*)(beta + k);
      float4 g4  = *(const float4*)(gamma + k);
      bw  = fmaf(wv4.x, b4.x, fmaf(wv4.y, b4.y, fmaf(wv4.z, b4.z, fmaf(wv4.w, b4.w, bw))));
      rsg = fmaf(wv4.x, S2LE * g4.x, fmaf(wv4.y, S2LE * g4.y,
            fmaf(wv4.z, S2LE * g4.z, fmaf(wv4.w, S2LE * g4.w, rsg))));
      #pragma unroll
      for (int kk = 0; kk < 4; kk++) {
        float wv = ((const float*)&wv4)[kk];
        const float* t0r = sOvl + (k + kk) * 10;
        #pragma unroll
        for (int xv = 0; xv < 10; xv++) ty[xv] = fmaf(wv, t0r[xv], ty[xv]);
      }
    }
    float ubn = update_b[n];
    sBW[n]  = S2LE * bw;
    sRSg[n] = rsg;
    #pragma unroll
    for (int xv = 0; xv < 10; xv++)
      sD1[xv * 260 + n] = S2LE * (ty[xv] + ubn + bw);
  }
  __syncthreads();

  // ---------- P3: sOW over T0 region; W_g frags + RSg into regs ----------
  f16*   sOW  = (f16*)sOvl;          // [8][64][8] = 8 KB
  float* sOut = sOvl + 2048;         // [4][16][16] = 4 KB
  for (int idx = tid; idx < 512; idx += 256) {
    int c = idx >> 6, l2 = idx & 63, q2 = l2 >> 4, o = l2 & 15;
    int k0 = c * 32 + q2 * 4;
    f16x8 f;
    #pragma unroll
    for (int j = 0; j < 8; j++) f[j] = (f16)0.f;
    if (o < OUTD) {
      const float* orow = out_w + o * HDIM;
      float4 a0 = *(const float4*)(orow + k0);
      float4 a1 = *(const float4*)(orow + k0 + 16);
      float4 g0 = *(const float4*)(gamma + k0);
      float4 g1 = *(const float4*)(gamma + k0 + 16);
      f[0]=(f16)(g0.x*a0.x); f[1]=(f16)(g0.y*a0.y); f[2]=(f16)(g0.z*a0.z); f[3]=(f16)(g0.w*a0.w);
      f[4]=(f16)(g1.x*a1.x); f[5]=(f16)(g1.y*a1.y); f[6]=(f16)(g1.z*a1.z); f[7]=(f16)(g1.w*a1.w);
    }
    *(f16x8*)(sOW + idx * 8) = f;
  }
  f16x8 wf[4][8];   // 128 VGPRs (the R1-verified budget)
  #pragma unroll
  for (int c = 0; c < 8; c++) {
    const int k0 = c * 32 + q * 4;
    float4 g0 = *(const float4*)(gamma + k0);
    float4 g1 = *(const float4*)(gamma + k0 + 16);
    #pragma unroll
    for (int nt = 0; nt < 4; nt++) {
      const float* wrow = update_w + (w * 64 + nt * 16 + ml) * HDIM;
      float4 a0 = *(const float4*)(wrow + k0);
      float4 a1 = *(const float4*)(wrow + k0 + 16);
      f16x8 f;
      f[0]=(f16)(S2LE*g0.x*a0.x); f[1]=(f16)(S2LE*g0.y*a0.y);
      f[2]=(f16)(S2LE*g0.z*a0.z); f[3]=(f16)(S2LE*g0.w*a0.w);
      f[4]=(f16)(S2LE*g1.x*a1.x); f[5]=(f16)(S2LE*g1.y*a1.y);
      f[6]=(f16)(S2LE*g1.z*a1.z); f[7]=(f16)(S2LE*g1.w*a1.w);
      wf[nt][c] = f;
    }
  }
  f32x4 rsgr[4];
  #pragma unroll
  for (int nt = 0; nt < 4; nt++)
    rsgr[nt] = *(const f32x4*)(sRSg + nb + nt * 16);

  // ---------- prologue t=0: y0 = D1[xv0] - sBW ----------
  f16x8 bf[8];
  f32x4 acc[4];
  float S1r, S2r;
  {
    const int xv0 = (int)sXb[0][ml];
    const float* dp = sD1 + xv0 * 260 + nb;
    float p1 = 0.f, p2 = 0.f;
    #pragma unroll
    for (int nt = 0; nt < 4; nt++) {
      f32x4 dd = *(const f32x4*)(dp + nt * 16);
      f32x4 bw = *(const f32x4*)(sBW + nb + nt * 16);
      #pragma unroll
      for (int r = 0; r < 4; r++) {
        float y  = dd[r] - bw[r];
        float e  = __builtin_amdgcn_exp2f(y);
        float tv = fmaf(-2.f, __builtin_amdgcn_rcpf(e + 1.f), 1.f);
        acc[nt][r] = tv;
        p1 += tv; p2 = fmaf(tv, tv, p2);
      }
    }
    p1 += __shfl_xor(p1, 16, 64); p2 += __shfl_xor(p2, 16, 64);
    p1 += __shfl_xor(p1, 32, 64); p2 += __shfl_xor(p2, 32, 64);
    if (l < 16) { sStats[0][w][ml][0] = p1; sStats[0][w][ml][1] = p2; }
    #pragma unroll
    for (int cc = 0; cc < 2; cc++) {
      f16x8 af;
      #pragma unroll
      for (int j = 0; j < 8; j++) af[j] = (f16)acc[2 * cc + (j >> 2)][j & 3];
      *(f16x8*)(&sFrag[0][2 * w + cc][l][0]) = af;
    }
    __syncthreads();
    #pragma unroll
    for (int c = 0; c < 8; c++) bf[c] = *(const f16x8*)(&sFrag[0][c][l][0]);
    S1r = sStats[0][0][ml][0] + sStats[0][1][ml][0] + sStats[0][2][ml][0] + sStats[0][3][ml][0];
    S2r = sStats[0][0][ml][1] + sStats[0][1][ml][1] + sStats[0][2][ml][1] + sStats[0][3][ml][1];
  }

  // ---------- main loop: ONE barrier per step ----------
  #pragma unroll 1
  for (int t = 1; t < TST; t++) {
    const int p  = t & 1;
    const int xv = (int)sXb[t][ml];
    float mu = S1r * (1.f / 256.f);
    float rs = __frsqrt_rn(fmaf(S2r, 1.f / 256.f, -mu * mu) + 1e-5f);
    float rsmu = rs * mu;
    const float* dp = sD1 + xv * 260 + nb;
    f32x4 bse[4];
    #pragma unroll
    for (int nt = 0; nt < 4; nt++) {
      f32x4 dd = *(const f32x4*)(dp + nt * 16);
      #pragma unroll
      for (int r = 0; r < 4; r++)
        bse[nt][r] = fmaf(-rsmu, rsgr[nt][r], dd[r]);
    }
    #pragma unroll
    for (int nt = 0; nt < 4; nt++) acc[nt] = (f32x4){0.f, 0.f, 0.f, 0.f};
    __builtin_amdgcn_s_setprio(1);
    #pragma unroll
    for (int c = 0; c < 8; c++) {
      #pragma unroll
      for (int nt = 0; nt < 4; nt++)
        acc[nt] = __builtin_amdgcn_mfma_f32_16x16x32_f16(wf[nt][c], bf[c], acc[nt], 0, 0, 0);
    }
    __builtin_amdgcn_s_setprio(0);
    float p1 = 0.f, p2 = 0.f;
    #pragma unroll
    for (int nt = 0; nt < 4; nt++) {
      #pragma unroll
      for (int r = 0; r < 4; r++) {
        float y  = fmaf(rs, acc[nt][r], bse[nt][r]);
        float e  = __builtin_amdgcn_exp2f(y);
        float tv = fmaf(-2.f, __builtin_amdgcn_rcpf(e + 1.f), 1.f);
        acc[nt][r] = tv;
        p1 += tv; p2 = fmaf(tv, tv, p2);
      }
    }
    p1 += __shfl_xor(p1, 16, 64); p2 += __shfl_xor(p2, 16, 64);
    p1 += __shfl_xor(p1, 32, 64); p2 += __shfl_xor(p2, 32, 64);
    if (l < 16) { sStats[p][w][ml][0] = p1; sStats[p][w][ml][1] = p2; }
    #pragma unroll
    for (int cc = 0; cc < 2; cc++) {
      f16x8 af;
      #pragma unroll
      for (int j = 0; j < 8; j++) af[j] = (f16)acc[2 * cc + (j >> 2)][j & 3];
      *(f16x8*)(&sFrag[p][2 * w + cc][l][0]) = af;
    }
    __syncthreads();
    #pragma unroll
    for (int c = 0; c < 8; c++) bf[c] = *(const f16x8*)(&sFrag[p][c][l][0]);
    S1r = sStats[p][0][ml][0] + sStats[p][1][ml][0] + sStats[p][2][ml][0] + sStats[p][3][ml][0];
    S2r = sStats[p][0][ml][1] + sStats[p][1][ml][1] + sStats[p][2][ml][1] + sStats[p][3][ml][1];
  }

  // ---------- output: partial MFMA per wave over its 2 chunks, LDS reduce ----------
  {
    float mu = S1r * (1.f / 256.f);
    float rs = __frsqrt_rn(fmaf(S2r, 1.f / 256.f, -mu * mu) + 1e-5f);
    f32x4 aO = {0.f, 0.f, 0.f, 0.f};
    #pragma unroll
    for (int cc = 0; cc < 2; cc++) {
      f16x8 af;
      #pragma unroll
      for (int j = 0; j < 8; j++)
        af[j] = (f16)((acc[2 * cc + (j >> 2)][j & 3] - mu) * rs);
      f16x8 of = *(const f16x8*)(sOW + ((2 * w + cc) * 64 + l) * 8);
      aO = __builtin_amdgcn_mfma_f32_16x16x32_f16(of, af, aO, 0, 0, 0);
    }
    #pragma unroll
    for (int r = 0; r < 4; r++)
      sOut[(w * 16 + ml) * 16 + q * 4 + r] = aO[r];
    __syncthreads();
    if (tid < 16 * OUTD) {
      int m = tid / OUTD, o = tid % OUTD;
      float s = sOut[(0 * 16 + m) * 16 + o] + sOut[(1 * 16 + m) * 16 + o]
              + sOut[(2 * 16 + m) * 16 + o] + sOut[(3 * 16 + m) * 16 + o];
      out[(size_t)(base + m) * OUTD + o] = s + sOB[o];
    }
  }
}

extern "C" void kernel_launch(void* const* d_in, const int* in_sizes, int n_in,
                              void* d_out, int out_size, void* d_ws, size_t ws_size,
                              hipStream_t stream) {
  const float* x   = (const float*)d_in[0];
  const float* ew  = (const float*)d_in[1];
  const float* eb  = (const float*)d_in[2];
  const float* uw  = (const float*)d_in[3];
  const float* ub  = (const float*)d_in[4];
  const float* g   = (const float*)d_in[5];
  const float* be  = (const float*)d_in[6];
  const float* ow  = (const float*)d_in[7];
  const float* ob  = (const float*)d_in[8];
  float* out = (float*)d_out;

  const int B = in_sizes[0] / TST;      // 16384
  const int grid = B / 16;              // 1024 blocks
  hipLaunchKernelGGL(rnn_kernel, dim3(grid), dim3(256), 0, stream,
                     x, ew, eb, uw, ub, g, be, ow, ob, out);
}